// Round 1
// baseline (998.987 us; speedup 1.0000x reference)
//
#include <hip/hip_runtime.h>

#define NN 8192      // nodes
#define SS 20        // seq len
#define DD 256       // feat dim = H
#define RGATE 1024   // 4H
#define KKD 512      // D + H

typedef __attribute__((ext_vector_type(8))) short short8;
typedef __attribute__((ext_vector_type(4))) float f32x4;

__device__ __forceinline__ unsigned short f2bf(float f) {
    unsigned int u = __float_as_uint(f);
    u += 0x7FFFu + ((u >> 16) & 1u);   // round-to-nearest-even
    return (unsigned short)(u >> 16);
}

__device__ __forceinline__ void async_copy16(const void* g, void* l) {
    __builtin_amdgcn_global_load_lds(
        (const __attribute__((address_space(1))) void*)g,
        (__attribute__((address_space(3))) void*)l, 16, 0, 0);
}

__device__ __forceinline__ float sigm(float x) { return 1.0f / (1.0f + __expf(-x)); }
// tanh via sigmoid form: graceful at both +/- extremes (no inf/inf NaN)
__device__ __forceinline__ float tanh_(float x) { return 2.0f / (1.0f + __expf(-2.0f * x)) - 1.0f; }

// ---------------------------------------------------------------------------
// Weight repack: Wcat[dir][r'][k], r' = 4*j + gate (gate-interleaved so a GEMM
// column tile of 128 covers 32 complete hidden units), k<256 -> w_ih, else w_hh.
// ---------------------------------------------------------------------------
__global__ void convert_w(const float* __restrict__ wihf, const float* __restrict__ whhf,
                          const float* __restrict__ bf,   const float* __restrict__ wihb,
                          const float* __restrict__ whhb, const float* __restrict__ bb,
                          unsigned short* __restrict__ Wcat, float* __restrict__ bperm) {
    const int idx = blockIdx.x * 256 + threadIdx.x;   // < 2*1024*512
    const int dir = idx >> 19;
    const int rem = idx & ((1 << 19) - 1);
    const int rp  = rem >> 9;          // r' in [0,1024)
    const int k   = rem & 511;
    const int j   = rp >> 2, gi = rp & 3;
    const int r   = gi * 256 + j;      // original row (PyTorch i,f,g,o blocks)
    const float* wih = dir ? wihb : wihf;
    const float* whh = dir ? whhb : whhf;
    const float v = (k < 256) ? wih[r * 256 + k] : whh[r * 256 + (k - 256)];
    Wcat[idx] = f2bf(v);
    if (k == 0) {
        const float* b = dir ? bb : bf;
        bperm[dir * 1024 + rp] = b[r];
    }
}

// ---------------------------------------------------------------------------
// Gather neighbor embeddings to bf16: X[t][n][256]
// ---------------------------------------------------------------------------
__global__ void gather_x(const float* __restrict__ emb, const int* __restrict__ idx,
                         unsigned short* __restrict__ X) {
    const int n = blockIdx.x, t = blockIdx.y;
    const int row = idx[n * SS + t];
    const float4* src = (const float4*)(emb + (size_t)row * DD);
    float4 v = src[threadIdx.x];
    ushort4 o;
    o.x = f2bf(v.x); o.y = f2bf(v.y); o.z = f2bf(v.z); o.w = f2bf(v.w);
    ((ushort4*)(X + ((size_t)t * NN + n) * DD))[threadIdx.x] = o;
}

// ---------------------------------------------------------------------------
// One LSTM step, both directions (blockIdx.z). GEMM: C[m, r'] =
// sum_k [x_t | h_prev][m,k] * Wcat[r',k]  (M=8192, R=1024, K=512), then fused
// cell update in epilogue. h double-buffered across steps (ping-pong) because
// column-blocks read all j of h_prev while owning only 32 j of h_next.
// ---------------------------------------------------------------------------
__global__ __launch_bounds__(256) void lstm_step(
    const unsigned short* __restrict__ X,      // [SS][NN][256] bf16
    const unsigned short* __restrict__ Wcat,   // [2][1024][512] bf16
    const float* __restrict__ bperm,           // [2][1024]
    unsigned short* __restrict__ hping,        // [2 ping][2 dir][NN][256] bf16
    float* __restrict__ cstate,                // [2 dir][NN][256] f32
    float* __restrict__ hsum,                  // [NN] f32
    int s) {
    const int dir = blockIdx.z;
    const int t = dir ? (SS - 1 - s) : s;
    const unsigned short* Xt    = X + (size_t)t * NN * DD;
    const unsigned short* hprev = hping + ((size_t)((s & 1) * 2 + dir)) * NN * 256;
    unsigned short*       hnext = hping + ((size_t)((((s + 1) & 1) * 2) + dir)) * NN * 256;
    const unsigned short* W     = Wcat + (size_t)dir * RGATE * KKD;
    const float*          bp    = bperm + dir * RGATE;
    float*                cdir  = cstate + (size_t)dir * NN * 256;

    __shared__ unsigned short As[128 * 64];   // 16 KB: A tile (rows=nodes, cols=k)
    __shared__ unsigned short Bs[128 * 64];   // 16 KB: B tile (rows=r', cols=k)

    const int tid  = threadIdx.x;
    const int lane = tid & 63;
    const int w    = tid >> 6;       // wave 0..3
    const int wm   = w >> 1, wn = w & 1;
    const int m0   = blockIdx.x * 128;
    const int n0   = blockIdx.y * 128;

    const int lrow = lane >> 3;        // row within 8-row staging chunk
    const int lcol = (lane & 7) * 8;   // bf16 col within 64-col tile

    f32x4 acc[4][4];
    #pragma unroll
    for (int i = 0; i < 4; ++i)
        #pragma unroll
        for (int j = 0; j < 4; ++j)
            acc[i][j] = f32x4{0.f, 0.f, 0.f, 0.f};

    for (int kt = 0; kt < 8; ++kt) {
        const int k0 = kt * 64;
        // A k-cols 0..255 come from X[t], 256..511 from h_prev
        const unsigned short* Abase = (kt < 4) ? (Xt + k0) : (hprev + (k0 - 256));
        #pragma unroll
        for (int q = 0; q < 4; ++q) {
            const int chunk = q * 4 + w;          // wave-uniform LDS chunk (1024 B)
            const int row   = chunk * 8 + lrow;   // 0..127
            async_copy16(Abase + (size_t)(m0 + row) * DD + lcol,
                         (void*)((char*)As + chunk * 1024));
            async_copy16(W + (size_t)(n0 + row) * KKD + k0 + lcol,
                         (void*)((char*)Bs + chunk * 1024));
        }
        __syncthreads();
        #pragma unroll
        for (int kk = 0; kk < 2; ++kk) {
            short8 af[4], bfr[4];
            const int kbyte = kk * 64 + ((lane >> 4) * 16);  // (kk*32 + quad*8)*2B
            #pragma unroll
            for (int mt = 0; mt < 4; ++mt) {
                const int r = wm * 64 + mt * 16 + (lane & 15);
                af[mt] = *(const short8*)((const char*)As + r * 128 + kbyte);
            }
            #pragma unroll
            for (int nt = 0; nt < 4; ++nt) {
                const int r = wn * 64 + nt * 16 + (lane & 15);
                bfr[nt] = *(const short8*)((const char*)Bs + r * 128 + kbyte);
            }
            #pragma unroll
            for (int mt = 0; mt < 4; ++mt)
                #pragma unroll
                for (int nt = 0; nt < 4; ++nt)
                    acc[mt][nt] = __builtin_amdgcn_mfma_f32_16x16x32_bf16(
                        af[mt], bfr[nt], acc[mt][nt], 0, 0, 0);
        }
        __syncthreads();
    }

    // Epilogue: per 16-row slab, stage C through LDS to regroup the 4 gate
    // columns (r' = 4j+gi) of each hidden unit into one lane, apply LSTM cell.
    float* eps   = (float*)As;          // reuse 16 KB = 4096 floats = 4 waves x 1024
    float* myeps = eps + w * 1024;      // 16 rows x 64 cols
    const int mloc_r = lane >> 2;       // 0..15
    const int jq     = lane & 3;        // group of 4 hidden units

    for (int mt = 0; mt < 4; ++mt) {
        #pragma unroll
        for (int nt = 0; nt < 4; ++nt) {
            #pragma unroll
            for (int v = 0; v < 4; ++v) {
                const int mloc = (lane >> 4) * 4 + v;        // C/D: row=quad*4+reg
                const int nloc = nt * 16 + (lane & 15);      //      col=lane&15
                myeps[mloc * 64 + nloc] = acc[mt][nt][v];
            }
        }
        __syncthreads();
        {
            const int mg  = m0 + wm * 64 + mt * 16 + mloc_r;            // node row
            const int jg0 = blockIdx.y * 32 + wn * 16 + jq * 4;         // first hidden j
            const f32x4* brow = (const f32x4*)(bp + 4 * jg0);
            float* cptr = cdir + (size_t)mg * 256 + jg0;
            f32x4 cold = *(const f32x4*)cptr;
            f32x4 cnew;
            float hv[4];
            #pragma unroll
            for (int jj = 0; jj < 4; ++jj) {
                f32x4 g  = *(const f32x4*)(myeps + mloc_r * 64 + jq * 16 + jj * 4);
                f32x4 bb = brow[jj];
                const float gi = sigm(g.x + bb.x);   // i
                const float gf = sigm(g.y + bb.y);   // f
                const float gg = tanh_(g.z + bb.z);  // g
                const float go = sigm(g.w + bb.w);   // o
                const float cn = gf * cold[jj] + gi * gg;
                cnew[jj] = cn;
                hv[jj] = go * tanh_(cn);
            }
            *(f32x4*)cptr = cnew;
            ushort4 hp;
            hp.x = f2bf(hv[0]); hp.y = f2bf(hv[1]); hp.z = f2bf(hv[2]); hp.w = f2bf(hv[3]);
            *(ushort4*)(hnext + (size_t)mg * 256 + jg0) = hp;
            float ssum = hv[0] + hv[1] + hv[2] + hv[3];
            ssum += __shfl_xor(ssum, 1);
            ssum += __shfl_xor(ssum, 2);
            if (jq == 0) atomicAdd(&hsum[mg], ssum);
        }
        __syncthreads();
    }
}

__global__ void bcast_out(const float* __restrict__ hsum, float* __restrict__ out) {
    const int n = blockIdx.x;
    const float v = hsum[n] * (1.0f / 512.0f);
    float2 p; p.x = v; p.y = v;
    ((float2*)(out + (size_t)n * 512))[threadIdx.x] = p;
}

extern "C" void kernel_launch(void* const* d_in, const int* in_sizes, int n_in,
                              void* d_out, int out_size, void* d_ws, size_t ws_size,
                              hipStream_t stream) {
    const float* emb  = (const float*)d_in[0];
    const float* wihf = (const float*)d_in[1];
    const float* whhf = (const float*)d_in[2];
    const float* bf   = (const float*)d_in[3];
    const float* wihb = (const float*)d_in[4];
    const float* whhb = (const float*)d_in[5];
    const float* bb   = (const float*)d_in[6];
    const int*   idx  = (const int*)d_in[7];
    float* out = (float*)d_out;

    // workspace layout (bytes)
    char* ws = (char*)d_ws;
    unsigned short* X     = (unsigned short*)(ws);               // 83,886,080  X[t][n][256] bf16
    unsigned short* Wcat  = (unsigned short*)(ws + 83886080);    //  2,097,152  [2][1024][512] bf16
    float*          bperm = (float*)(ws + 85983232);             //      8,192  [2][1024] f32
    unsigned short* hping = (unsigned short*)(ws + 85991424);    // 16,777,216  [2][2][8192][256] bf16
    float*          cst   = (float*)(ws + 102768640);            // 16,777,216  [2][8192][256] f32
    float*          hsum  = (float*)(ws + 119545856);            //     32,768  [8192] f32
    // total: 119,578,624 B

    hipMemsetAsync(hping, 0, 8388608, stream);                   // h ping0, both dirs
    hipMemsetAsync(cst, 0, 16777216 + 32768, stream);            // c + hsum (contiguous)

    convert_w<<<4096, 256, 0, stream>>>(wihf, whhf, bf, wihb, whhb, bb, Wcat, bperm);
    gather_x<<<dim3(NN, SS), 64, 0, stream>>>(emb, idx, X);
    for (int s = 0; s < SS; ++s)
        lstm_step<<<dim3(64, 8, 2), 256, 0, stream>>>(X, Wcat, bperm, hping, cst, hsum, s);
    bcast_out<<<NN, 256, 0, stream>>>(hsum, out);
}